// Round 5
// baseline (349.751 us; speedup 1.0000x reference)
//
#include <hip/hip_runtime.h>
#include <hip/hip_fp16.h>
#include <cmath>

#define H 128
#define GAMMA 0.1f
#define EPS 0.1f
#define NEG 0.01f
#define NGRAPH 256
#define SLOT 64          // u16 slots per csr row: [cnt, src0..src62]
#define CAPE 63          // max stored edges per node (P(deg>=64) ~ 1e-26)

typedef _Float16 half_t;
typedef _Float16 f16x8 __attribute__((ext_vector_type(8)));
typedef _Float16 f16x4 __attribute__((ext_vector_type(4)));
typedef _Float16 f16x2 __attribute__((ext_vector_type(2)));
typedef float f32x4 __attribute__((ext_vector_type(4)));
typedef float f32x2 __attribute__((ext_vector_type(2)));
typedef float f32x8 __attribute__((ext_vector_type(8)));

__device__ __forceinline__ float fast_tanh(float v) {
    float e = __builtin_amdgcn_exp2f(v * 2.8853900817779268f);
    float r = __builtin_amdgcn_rcpf(e + 1.0f);
    return 1.0f - 2.0f * r;
}

// 8 fp8 (e4m3, 2 dwords) -> 8 f32
__device__ __forceinline__ f32x8 cvt_fp8x8(int2 d) {
    f32x2 p0 = __builtin_amdgcn_cvt_pk_f32_fp8(d.x, false);
    f32x2 p1 = __builtin_amdgcn_cvt_pk_f32_fp8(d.x, true);
    f32x2 p2 = __builtin_amdgcn_cvt_pk_f32_fp8(d.y, false);
    f32x2 p3 = __builtin_amdgcn_cvt_pk_f32_fp8(d.y, true);
    f32x8 r;
    r[0] = p0.x; r[1] = p0.y; r[2] = p1.x; r[3] = p1.y;
    r[4] = p2.x; r[5] = p2.y; r[6] = p3.x; r[7] = p3.y;
    return r;
}

// butterfly add of f32x8 from lane^mask
__device__ __forceinline__ f32x8 xor_addf(f32x8 v, int mask) {
    f32x8 r;
#pragma unroll
    for (int k = 0; k < 8; ++k) r[k] = v[k] + __shfl_xor(v[k], mask, 64);
    return r;
}

// ---------------- fused (grid-stride): weights->fragment order, x0->f16 AND
// x0->fp8 shadow, deg=0.
// B-fragment order with PERMUTED output cols: tile ct covers cols j = m*8+ct
// (m = lane&15) so the MFMA C-layout gives each lane 8 consecutive cols ->
// vectorized epilogue. WtTf[((s*8+ct)*64+lane)*8+t] = M[j][k],
// j=(lane&15)*8+ct, k=s*32+(lane>>4)*8+t.
// M[j][k] = (k<H) ? W[j][k]-W[k][j]-gamma*delta(j,k) : lin_w[j][k-H]
__global__ __launch_bounds__(256) void prep_cast_zero(
        const float* __restrict__ W, const float* __restrict__ lin_w,
        half_t* __restrict__ WtTf, const float* __restrict__ x,
        half_t* __restrict__ xh, unsigned char* __restrict__ xq,
        int n4, int* __restrict__ deg, int N) {
    int stride = gridDim.x * 256;
    int tot = max(n4, max(32768, N));
    for (int i = blockIdx.x * 256 + threadIdx.x; i < tot; i += stride) {
        if (i < n4) {
            float4 v = *(const float4*)(x + (size_t)i * 4);
            half_t* o = xh + (size_t)i * 4;
            o[0] = (half_t)v.x; o[1] = (half_t)v.y; o[2] = (half_t)v.z; o[3] = (half_t)v.w;
            int w = __builtin_amdgcn_cvt_pk_fp8_f32(v.x, v.y, 0, false);
            w = __builtin_amdgcn_cvt_pk_fp8_f32(v.z, v.w, w, true);
            *(int*)(xq + (size_t)i * 4) = w;
        }
        if (i < 32768) {
            int t = i & 7;
            int lane = (i >> 3) & 63;
            int ct = (i >> 9) & 7;
            int s = i >> 12;
            int q = lane >> 4, m = lane & 15;
            int j = m * 8 + ct;                  // permuted col mapping
            int k = s * 32 + q * 8 + t;
            float v;
            if (k < H) v = W[j * H + k] - W[k * H + j] - (j == k ? GAMMA : 0.f);
            else       v = lin_w[j * H + (k - H)];
            WtTf[i] = (half_t)v;
        }
        if (i < N) deg[i] = 0;
    }
}

// ---------------- direct fixed-capacity CSR fill; srcs land at slots 1..63
__global__ __launch_bounds__(256) void fill_direct(const int* __restrict__ src,
        const int* __restrict__ dst, int* __restrict__ deg,
        unsigned short* __restrict__ csr, int E) {
    int e = blockIdx.x * 256 + threadIdx.x;
    if (e < E) {
        int d = dst[e];
        int p = atomicAdd(&deg[d], 1);
        if (p < CAPE) csr[(size_t)d * SLOT + 1 + p] = (unsigned short)src[e];
    }
}

// ---------------- write cnt into csr row slot 0 (sequential, cheap)
__global__ __launch_bounds__(256) void deg2csr(const int* __restrict__ deg,
        unsigned short* __restrict__ csr, int N) {
    int i = blockIdx.x * 256 + threadIdx.x;
    if (i < N) csr[(size_t)i * SLOT] = (unsigned short)min(deg[i], CAPE);
}

// ---------------- gather aggregation v5: fp8 rows + f32 accumulate.
// csr row = [cnt, src0..src62] (128B): one wave-wide u16 load delivers count
// AND indices. Nodes (2w, 2w+1) per wave, rows prefetched. ds_bpermute fans
// 4 edge indices to four 16-lane groups; each lane loads int2 (8B of fp8)
// -> 128B burst per edge (HALF the fp16 traffic), converts via
// v_cvt_pk_f32_fp8 and accumulates in f32 (more accurate than the old f16
// pk-add chain, offsetting fp8 storage error).
__global__ __launch_bounds__(256) void gather_agg(const unsigned char* __restrict__ xq,
        const unsigned short* __restrict__ csr, half_t* __restrict__ xaggh, int N) {
    int wid = blockIdx.x * 4 + (threadIdx.x >> 6);
    int nw = gridDim.x * 4;
    int lane = threadIdx.x & 63;
    int g = lane >> 4, fl = lane & 15;

    int node = wid * 2;
    if (node >= N) return;
    int rA = (int)csr[(size_t)node * SLOT + lane];
    int rB = (node + 1 < N) ? (int)csr[(size_t)(node + 1) * SLOT + lane] : 0;

    while (true) {
        int curA = rA, curB = rB;
        int hasB = (node + 1 < N);
        int nxt = node + 2 * nw;
        if (nxt < N) {           // prefetch next pair's rows
            rA = (int)csr[(size_t)nxt * SLOT + lane];
            rB = (nxt + 1 < N) ? (int)csr[(size_t)(nxt + 1) * SLOT + lane] : 0;
        }
        int cntA = __builtin_amdgcn_readfirstlane(curA);
        int cntB = hasB ? __builtin_amdgcn_readfirstlane(curB) : 0;

        f32x8 aA0 = (f32x8)(0.f), aA1 = (f32x8)(0.f);
        f32x8 aB0 = (f32x8)(0.f), aB1 = (f32x8)(0.f);
        int jA = 0, jB = 0;
        // interleaved 4-edge steps: 2 bpermutes + 2 independent 8B loads
        while (jA + 3 < cntA && jB + 3 < cntB) {
            int iA = __builtin_amdgcn_ds_bpermute((1 + jA + g) << 2, curA);
            int iB = __builtin_amdgcn_ds_bpermute((1 + jB + g) << 2, curB);
            int2 dA = *(const int2*)(xq + (size_t)iA * H + fl * 8);
            int2 dB = *(const int2*)(xq + (size_t)iB * H + fl * 8);
            aA0 += cvt_fp8x8(dA); aB0 += cvt_fp8x8(dB);
            jA += 4; jB += 4;
        }
        while (jA + 3 < cntA) {
            int iA = __builtin_amdgcn_ds_bpermute((1 + jA + g) << 2, curA);
            int2 dA = *(const int2*)(xq + (size_t)iA * H + fl * 8);
            aA1 += cvt_fp8x8(dA);
            jA += 4;
        }
        while (jB + 3 < cntB) {
            int iB = __builtin_amdgcn_ds_bpermute((1 + jB + g) << 2, curB);
            int2 dB = *(const int2*)(xq + (size_t)iB * H + fl * 8);
            aB1 += cvt_fp8x8(dB);
            jB += 4;
        }
        int remA = cntA - jA;   // 0..3
        if (remA > 0) {
            int iA = __builtin_amdgcn_ds_bpermute((1 + jA + min(g, remA - 1)) << 2, curA);
            int2 dA = *(const int2*)(xq + (size_t)iA * H + fl * 8);
            if (g < remA) aA1 += cvt_fp8x8(dA);
        }
        int remB = cntB - jB;
        if (remB > 0) {
            int iB = __builtin_amdgcn_ds_bpermute((1 + jB + min(g, remB - 1)) << 2, curB);
            int2 dB = *(const int2*)(xq + (size_t)iB * H + fl * 8);
            if (g < remB) aB1 += cvt_fp8x8(dB);
        }

        f32x8 accA = aA0 + aA1;
        accA = xor_addf(accA, 16);
        accA = xor_addf(accA, 32);
        if (lane < 16) {
            f16x8 h;
#pragma unroll
            for (int k = 0; k < 8; ++k) h[k] = (half_t)accA[k];
            *(f16x8*)(xaggh + (size_t)node * H + fl * 8) = h;
        }
        if (hasB) {
            f32x8 accB = aB0 + aB1;
            accB = xor_addf(accB, 16);
            accB = xor_addf(accB, 32);
            if (lane < 16) {
                f16x8 h;
#pragma unroll
                for (int k = 0; k < 8; ++k) h[k] = (half_t)accB[k];
                *(f16x8*)(xaggh + (size_t)(node + 1) * H + fl * 8) = h;
            }
        }
        if (nxt >= N) break;
        node = nxt;
    }
}

// ---------------- conv+update: 4 waves x 16 rows = 64 rows per block, acc[8]
// only (low VGPR -> high occupancy). Permuted B layout gives lane 8
// consecutive output cols -> f16x8 vector residual load + store. Epilogue
// additionally emits the fp8 shadow row for the next iteration's gather.
#define CROWS 64
__global__ __launch_bounds__(256) void conv_mfma(
        const half_t* __restrict__ xh, const half_t* __restrict__ xaggh,
        const half_t* __restrict__ WtTf, const float* __restrict__ bias,
        half_t* __restrict__ xhout, unsigned char* __restrict__ xqout, int N) {
    int tid = threadIdx.x;
    int wave = tid >> 6, lane = tid & 63;
    int q = lane >> 4, m = lane & 15;
    int n0 = blockIdx.x * CROWS + wave * 16;

    f32x4 acc[8];
#pragma unroll
    for (int ct = 0; ct < 8; ++ct) acc[ct] = (f32x4){0.f, 0.f, 0.f, 0.f};

    int arow = min(n0 + m, N - 1);
#pragma unroll
    for (int s = 0; s < 8; ++s) {
        f16x8 afrag = (s < 4)
            ? *(const f16x8*)(xh    + (size_t)arow * H + s * 32 + q * 8)
            : *(const f16x8*)(xaggh + (size_t)arow * H + (s - 4) * 32 + q * 8);
#pragma unroll
        for (int ct = 0; ct < 8; ++ct) {
            f16x8 bfrag = *(const f16x8*)(WtTf + ((s * 8 + ct) * 64 + lane) * 8);
            acc[ct] = __builtin_amdgcn_mfma_f32_16x16x32_f16(afrag, bfrag, acc[ct], 0, 0, 0);
        }
    }

    // epilogue: lane (q,m), reg r -> row n0+q*4+r, cols m*8 .. m*8+7
    float4 b0 = *(const float4*)(bias + m * 8);
    float4 b1 = *(const float4*)(bias + m * 8 + 4);
    float bb[8] = {b0.x, b0.y, b0.z, b0.w, b1.x, b1.y, b1.z, b1.w};
#pragma unroll
    for (int r = 0; r < 4; ++r) {
        int row = n0 + q * 4 + r;
        if (row < N) {
            f16x8 xr = *(const f16x8*)(xh + (size_t)row * H + m * 8);
            f16x8 o;
            float fv[8];
#pragma unroll
            for (int ct = 0; ct < 8; ++ct) {
                float c = acc[ct][r] + bb[ct];
                float val = (float)xr[ct] + EPS * fast_tanh(c);
                o[ct] = (half_t)val;
                fv[ct] = val;
            }
            *(f16x8*)(xhout + (size_t)row * H + m * 8) = o;
            int lo = __builtin_amdgcn_cvt_pk_fp8_f32(fv[0], fv[1], 0, false);
            lo = __builtin_amdgcn_cvt_pk_fp8_f32(fv[2], fv[3], lo, true);
            int hi = __builtin_amdgcn_cvt_pk_fp8_f32(fv[4], fv[5], 0, false);
            hi = __builtin_amdgcn_cvt_pk_fp8_f32(fv[6], fv[7], hi, true);
            *(int2*)(xqout + (size_t)row * H + m * 8) = make_int2(lo, hi);
        }
    }
}

// ---------------- fused triple pooling + 2-layer MLP (one block per graph)
__global__ __launch_bounds__(1024) void pool_mlp(const half_t* __restrict__ x,
        const int* __restrict__ batch,
        const float* __restrict__ l1_w, const float* __restrict__ l1_b,
        const float* __restrict__ l2_w, const float* __restrict__ l2_b,
        float* __restrict__ out, int N) {
    __shared__ float ssum[8][128];
    __shared__ float smax[8][128];
    __shared__ __align__(16) float sp[384];
    __shared__ __align__(16) float sh[192];
    int g = blockIdx.x, t = threadIdx.x;
    int feat = t & 127, slot = t >> 7;   // 8 slots
    int lo = 0, hi = N;
    while (lo < hi) { int mid = (lo + hi) >> 1; if (batch[mid] < g) lo = mid + 1; else hi = mid; }
    int start = lo;
    hi = N;
    while (lo < hi) { int mid = (lo + hi) >> 1; if (batch[mid] < g + 1) lo = mid + 1; else hi = mid; }
    int end = lo;
    float sum = 0.f, mx = -INFINITY;
    for (int n = start + slot; n < end; n += 8) {
        float v = (float)x[(size_t)n * H + feat];
        sum += v;
        mx = fmaxf(mx, v);
    }
    ssum[slot][feat] = sum;
    smax[slot][feat] = mx;
    __syncthreads();
    if (t < 128) {
        float s = 0.f, m = -INFINITY;
#pragma unroll
        for (int k = 0; k < 8; ++k) { s += ssum[k][t]; m = fmaxf(m, smax[k][t]); }
        int cnt = end - start;
        sp[t] = s;
        sp[128 + t] = (cnt > 0) ? m : 0.f;
        sp[256 + t] = s / (float)(cnt > 0 ? cnt : 1);
    }
    __syncthreads();
    if (t < 192) {
        float acc = l1_b[t];
        const float* wr = l1_w + (size_t)t * 384;
        for (int k = 0; k < 384; k += 4) {
            float4 w = *(const float4*)(wr + k);
            float4 p = *(const float4*)(sp + k);
            acc += w.x * p.x + w.y * p.y + w.z * p.z + w.w * p.w;
        }
        sh[t] = acc > 0.f ? acc : NEG * acc;
    }
    __syncthreads();
    if (t < 64) {
        float acc = l2_b[t];
        const float* wr = l2_w + (size_t)t * 192;
        for (int k = 0; k < 192; k += 4) {
            float4 w = *(const float4*)(wr + k);
            float4 p = *(const float4*)(sh + k);
            acc += w.x * p.x + w.y * p.y + w.z * p.z + w.w * p.w;
        }
        out[g * 64 + t] = acc > 0.f ? acc : NEG * acc;
    }
}

extern "C" void kernel_launch(void* const* d_in, const int* in_sizes, int n_in,
                              void* d_out, int out_size, void* d_ws, size_t ws_size,
                              hipStream_t stream) {
    const float* x0    = (const float*)d_in[0];
    const int*   edge  = (const int*)d_in[1];
    const int*   batch = (const int*)d_in[2];
    const float* W     = (const float*)d_in[3];
    const float* bias  = (const float*)d_in[4];
    const float* lin_w = (const float*)d_in[5];
    const float* l1_w  = (const float*)d_in[6];
    const float* l1_b  = (const float*)d_in[7];
    const float* l2_w  = (const float*)d_in[8];
    const float* l2_b  = (const float*)d_in[9];
    float* out = (float*)d_out;

    int N = in_sizes[0] / H;
    int E = in_sizes[1] / 2;
    const int* src = edge;
    const int* dst = edge + E;

    size_t nh = (size_t)N * H;
    half_t* xhA    = (half_t*)d_ws;
    half_t* xhB    = xhA + nh;
    half_t* xaggh  = xhB + nh;
    half_t* WtTf   = xaggh + nh;              // 32768 halfs
    int* deg       = (int*)(WtTf + 32768);
    unsigned short* csr = (unsigned short*)(deg + N);   // N*SLOT u16
    unsigned char* xq   = (unsigned char*)(csr + (size_t)N * SLOT);  // N*H fp8

    int n4 = (int)(nh / 4);
    prep_cast_zero<<<1024, 256, 0, stream>>>(W, lin_w, WtTf, x0, xhA, xq, n4, deg, N);

    fill_direct<<<(E + 255) / 256, 256, 0, stream>>>(src, dst, deg, csr, E);
    deg2csr<<<(N + 255) / 256, 256, 0, stream>>>(deg, csr, N);

    const half_t* xcur_h = xhA;
    int nblocks = (N + CROWS - 1) / CROWS;
    for (int it = 0; it < 5; ++it) {
        gather_agg<<<2048, 256, 0, stream>>>(xq, csr, xaggh, N);
        half_t* xnext_h = (it & 1) ? xhA : xhB;
        conv_mfma<<<nblocks, 256, 0, stream>>>(xcur_h, xaggh, WtTf, bias, xnext_h, xq, N);
        xcur_h = xnext_h;
    }

    pool_mlp<<<NGRAPH, 1024, 0, stream>>>(xcur_h, batch, l1_w, l1_b, l2_w, l2_b, out, N);
}

// Round 7
// 341.682 us; speedup vs baseline: 1.0236x; 1.0236x over previous
//
#include <hip/hip_runtime.h>
#include <hip/hip_fp16.h>
#include <cmath>

#define H 128
#define GAMMA 0.1f
#define EPS 0.1f
#define NEG 0.01f
#define NGRAPH 256
#define ROWU16 64        // u16 slots per csr row: [cnt(int) = slots 0-1][src x62]
#define CAPE 62          // max stored edges per node (P(deg>=62) ~ 1e-25)

typedef _Float16 half_t;
typedef _Float16 f16x8 __attribute__((ext_vector_type(8)));
typedef _Float16 f16x2 __attribute__((ext_vector_type(2)));
typedef __fp16 fp16v2 __attribute__((ext_vector_type(2)));   // cvt_pkrtz return type
typedef float f32x4 __attribute__((ext_vector_type(4)));
typedef float f32x2 __attribute__((ext_vector_type(2)));

__device__ __forceinline__ float fast_tanh(float v) {
    float e = __builtin_amdgcn_exp2f(v * 2.8853900817779268f);
    float r = __builtin_amdgcn_rcpf(e + 1.0f);
    return 1.0f - 2.0f * r;
}

// f32 pair -> packed f16x2 bits (as int), via the builtin's native return type
__device__ __forceinline__ int pkrtz_bits(float x, float y) {
    union { fp16v2 h; int i; } u;
    u.h = __builtin_amdgcn_cvt_pkrtz(x, y);
    return u.i;
}

// ---------------- fused (grid-stride): weights->fragment order, x0->f16 AND
// x0->fp8 shadow, csr row-counters = 0.
// B-fragment order with PERMUTED output cols: tile ct covers cols j = m*8+ct
// (m = lane&15) so the MFMA C-layout gives each lane 8 consecutive cols ->
// vectorized epilogue. WtTf[((s*8+ct)*64+lane)*8+t] = M[j][k],
// j=(lane&15)*8+ct, k=s*32+(lane>>4)*8+t.
// M[j][k] = (k<H) ? W[j][k]-W[k][j]-gamma*delta(j,k) : lin_w[j][k-H]
__global__ __launch_bounds__(256) void prep_cast_zero(
        const float* __restrict__ W, const float* __restrict__ lin_w,
        half_t* __restrict__ WtTf, const float* __restrict__ x,
        half_t* __restrict__ xh, unsigned char* __restrict__ xq,
        unsigned short* __restrict__ csr, int n4, int N) {
    int stride = gridDim.x * 256;
    int tot = max(n4, max(32768, N));
    for (int i = blockIdx.x * 256 + threadIdx.x; i < tot; i += stride) {
        if (i < n4) {
            float4 v = *(const float4*)(x + (size_t)i * 4);
            half_t* o = xh + (size_t)i * 4;
            o[0] = (half_t)v.x; o[1] = (half_t)v.y; o[2] = (half_t)v.z; o[3] = (half_t)v.w;
            int w = __builtin_amdgcn_cvt_pk_fp8_f32(v.x, v.y, 0, false);
            w = __builtin_amdgcn_cvt_pk_fp8_f32(v.z, v.w, w, true);
            *(int*)(xq + (size_t)i * 4) = w;
        }
        if (i < 32768) {
            int t = i & 7;
            int lane = (i >> 3) & 63;
            int ct = (i >> 9) & 7;
            int s = i >> 12;
            int q = lane >> 4, m = lane & 15;
            int j = m * 8 + ct;                  // permuted col mapping
            int k = s * 32 + q * 8 + t;
            float v;
            if (k < H) v = W[j * H + k] - W[k * H + j] - (j == k ? GAMMA : 0.f);
            else       v = lin_w[j * H + (k - H)];
            WtTf[i] = (half_t)v;
        }
        if (i < N) *(int*)(csr + (size_t)i * ROWU16) = 0;   // zero row counter
    }
}

// ---------------- CSR fill, counter embedded in the row: the atomicAdd and
// the u16 slot-write land in the SAME 64B line for p<30 (and same 128B row
// always) -> ~1 random line per edge instead of 2.
__global__ __launch_bounds__(256) void fill_direct(const int* __restrict__ src,
        const int* __restrict__ dst, unsigned short* __restrict__ csr, int E) {
    int e = blockIdx.x * 256 + threadIdx.x;
    if (e < E) {
        int d = dst[e];
        int* rowcnt = (int*)(csr + (size_t)d * ROWU16);
        int p = atomicAdd(rowcnt, 1);
        if (p < CAPE) ((unsigned short*)rowcnt)[2 + p] = (unsigned short)src[e];
    }
}

// ---------------- gather v6: 8 edges per load instruction, fp8 rows, cheap
// accumulate. lane = (slot = lane>>3 in 0..7, chunk = lane&7). One ds_bpermute
// per 8-edge step gives every lane its slot's src index (per-lane pull); one
// dwordx4 load covers 8 edges x 16B fp8 = 8 distinct 128B rows (16 lines).
// Per edge: 0.125 VMEM instr, 2 lines, ~4.5 VALU cycles (8 cvt_pk_f32_fp8 +
// 8 pk_f32 adds per 8 edges). Node end: pack f32->f16 (pkrtz), 3-round
// shfl_xor tree over slots, 8 surviving lanes write the 256B agg row.
// Node pair per wave + next-pair row prefetch as before.
__global__ __launch_bounds__(256) void gather_agg(const unsigned char* __restrict__ xq,
        const unsigned short* __restrict__ csr, half_t* __restrict__ xaggh, int N) {
    int wid = blockIdx.x * 4 + (threadIdx.x >> 6);
    int nw = gridDim.x * 4;
    int lane = threadIdx.x & 63;
    int slot = lane >> 3, chunk = lane & 7;

    int node = wid * 2;
    if (node >= N) return;
    int rA = (int)csr[(size_t)node * ROWU16 + lane];
    int rB = (node + 1 < N) ? (int)csr[(size_t)(node + 1) * ROWU16 + lane] : 0;

    while (true) {
        int curA = rA, curB = rB;
        int hasB = (node + 1 < N);
        int nxt = node + 2 * nw;
        if (nxt < N) {           // prefetch next pair's rows
            rA = (int)csr[(size_t)nxt * ROWU16 + lane];
            rB = (nxt + 1 < N) ? (int)csr[(size_t)(nxt + 1) * ROWU16 + lane] : 0;
        }
        int cntA = min(__builtin_amdgcn_readlane(curA, 0) |
                       (__builtin_amdgcn_readlane(curA, 1) << 16), CAPE);
        int cntB = hasB ? min(__builtin_amdgcn_readlane(curB, 0) |
                              (__builtin_amdgcn_readlane(curB, 1) << 16), CAPE) : 0;

        f32x2 aA[8], aB[8];
#pragma unroll
        for (int k = 0; k < 8; ++k) { aA[k] = (f32x2){0.f, 0.f}; aB[k] = (f32x2){0.f, 0.f}; }

        int bA = 0, bB = 0;
        // interleaved: one 8-edge step for A and one for B -> 2 loads in flight
        while (bA < cntA && bB < cntB) {
            int iA = __builtin_amdgcn_ds_bpermute((2 + min(bA + slot, cntA - 1)) << 2, curA);
            int iB = __builtin_amdgcn_ds_bpermute((2 + min(bB + slot, cntB - 1)) << 2, curB);
            int4 dA = *(const int4*)(xq + (size_t)iA * H + chunk * 16);
            int4 dB = *(const int4*)(xq + (size_t)iB * H + chunk * 16);
            if (bA + slot < cntA) {
                aA[0] += __builtin_amdgcn_cvt_pk_f32_fp8(dA.x, false);
                aA[1] += __builtin_amdgcn_cvt_pk_f32_fp8(dA.x, true);
                aA[2] += __builtin_amdgcn_cvt_pk_f32_fp8(dA.y, false);
                aA[3] += __builtin_amdgcn_cvt_pk_f32_fp8(dA.y, true);
                aA[4] += __builtin_amdgcn_cvt_pk_f32_fp8(dA.z, false);
                aA[5] += __builtin_amdgcn_cvt_pk_f32_fp8(dA.z, true);
                aA[6] += __builtin_amdgcn_cvt_pk_f32_fp8(dA.w, false);
                aA[7] += __builtin_amdgcn_cvt_pk_f32_fp8(dA.w, true);
            }
            if (bB + slot < cntB) {
                aB[0] += __builtin_amdgcn_cvt_pk_f32_fp8(dB.x, false);
                aB[1] += __builtin_amdgcn_cvt_pk_f32_fp8(dB.x, true);
                aB[2] += __builtin_amdgcn_cvt_pk_f32_fp8(dB.y, false);
                aB[3] += __builtin_amdgcn_cvt_pk_f32_fp8(dB.y, true);
                aB[4] += __builtin_amdgcn_cvt_pk_f32_fp8(dB.z, false);
                aB[5] += __builtin_amdgcn_cvt_pk_f32_fp8(dB.z, true);
                aB[6] += __builtin_amdgcn_cvt_pk_f32_fp8(dB.w, false);
                aB[7] += __builtin_amdgcn_cvt_pk_f32_fp8(dB.w, true);
            }
            bA += 8; bB += 8;
        }
        while (bA < cntA) {
            int iA = __builtin_amdgcn_ds_bpermute((2 + min(bA + slot, cntA - 1)) << 2, curA);
            int4 dA = *(const int4*)(xq + (size_t)iA * H + chunk * 16);
            if (bA + slot < cntA) {
                aA[0] += __builtin_amdgcn_cvt_pk_f32_fp8(dA.x, false);
                aA[1] += __builtin_amdgcn_cvt_pk_f32_fp8(dA.x, true);
                aA[2] += __builtin_amdgcn_cvt_pk_f32_fp8(dA.y, false);
                aA[3] += __builtin_amdgcn_cvt_pk_f32_fp8(dA.y, true);
                aA[4] += __builtin_amdgcn_cvt_pk_f32_fp8(dA.z, false);
                aA[5] += __builtin_amdgcn_cvt_pk_f32_fp8(dA.z, true);
                aA[6] += __builtin_amdgcn_cvt_pk_f32_fp8(dA.w, false);
                aA[7] += __builtin_amdgcn_cvt_pk_f32_fp8(dA.w, true);
            }
            bA += 8;
        }
        while (bB < cntB) {
            int iB = __builtin_amdgcn_ds_bpermute((2 + min(bB + slot, cntB - 1)) << 2, curB);
            int4 dB = *(const int4*)(xq + (size_t)iB * H + chunk * 16);
            if (bB + slot < cntB) {
                aB[0] += __builtin_amdgcn_cvt_pk_f32_fp8(dB.x, false);
                aB[1] += __builtin_amdgcn_cvt_pk_f32_fp8(dB.x, true);
                aB[2] += __builtin_amdgcn_cvt_pk_f32_fp8(dB.y, false);
                aB[3] += __builtin_amdgcn_cvt_pk_f32_fp8(dB.y, true);
                aB[4] += __builtin_amdgcn_cvt_pk_f32_fp8(dB.z, false);
                aB[5] += __builtin_amdgcn_cvt_pk_f32_fp8(dB.z, true);
                aB[6] += __builtin_amdgcn_cvt_pk_f32_fp8(dB.w, false);
                aB[7] += __builtin_amdgcn_cvt_pk_f32_fp8(dB.w, true);
            }
            bB += 8;
        }

        // pack to f16 pairs, tree-reduce over slots (masks 8,16,32), write.
#pragma unroll
        for (int half = 0; half < 2; ++half) {
            f32x2* a = half ? aB : aA;
            if (half && !hasB) break;
            union { f16x2 h; int i; } t[8];
#pragma unroll
            for (int k = 0; k < 8; ++k) t[k].i = pkrtz_bits(a[k].x, a[k].y);
#pragma unroll
            for (int m = 8; m <= 32; m <<= 1) {
#pragma unroll
                for (int k = 0; k < 8; ++k) {
                    union { f16x2 h; int i; } o;
                    o.i = __shfl_xor(t[k].i, m, 64);
                    t[k].h += o.h;
                }
            }
            if (lane < 8) {
                union { int i[4]; f16x8 v; } lo, hi;
#pragma unroll
                for (int k = 0; k < 4; ++k) { lo.i[k] = t[k].i; hi.i[k] = t[k + 4].i; }
                half_t* dst = xaggh + (size_t)(node + half) * H + chunk * 16;
                *(f16x8*)dst = lo.v;
                *(f16x8*)(dst + 8) = hi.v;
            }
        }

        if (nxt >= N) break;
        node = nxt;
    }
}

// ---------------- conv+update: 4 waves x 16 rows = 64 rows per block, acc[8]
// only (low VGPR -> high occupancy). Permuted B layout gives lane 8
// consecutive output cols -> f16x8 vector residual load + store. Epilogue
// additionally emits the fp8 shadow row for the next iteration's gather.
#define CROWS 64
__global__ __launch_bounds__(256) void conv_mfma(
        const half_t* __restrict__ xh, const half_t* __restrict__ xaggh,
        const half_t* __restrict__ WtTf, const float* __restrict__ bias,
        half_t* __restrict__ xhout, unsigned char* __restrict__ xqout, int N) {
    int tid = threadIdx.x;
    int wave = tid >> 6, lane = tid & 63;
    int q = lane >> 4, m = lane & 15;
    int n0 = blockIdx.x * CROWS + wave * 16;

    f32x4 acc[8];
#pragma unroll
    for (int ct = 0; ct < 8; ++ct) acc[ct] = (f32x4){0.f, 0.f, 0.f, 0.f};

    int arow = min(n0 + m, N - 1);
#pragma unroll
    for (int s = 0; s < 8; ++s) {
        f16x8 afrag = (s < 4)
            ? *(const f16x8*)(xh    + (size_t)arow * H + s * 32 + q * 8)
            : *(const f16x8*)(xaggh + (size_t)arow * H + (s - 4) * 32 + q * 8);
#pragma unroll
        for (int ct = 0; ct < 8; ++ct) {
            f16x8 bfrag = *(const f16x8*)(WtTf + ((s * 8 + ct) * 64 + lane) * 8);
            acc[ct] = __builtin_amdgcn_mfma_f32_16x16x32_f16(afrag, bfrag, acc[ct], 0, 0, 0);
        }
    }

    // epilogue: lane (q,m), reg r -> row n0+q*4+r, cols m*8 .. m*8+7
    float4 b0 = *(const float4*)(bias + m * 8);
    float4 b1 = *(const float4*)(bias + m * 8 + 4);
    float bb[8] = {b0.x, b0.y, b0.z, b0.w, b1.x, b1.y, b1.z, b1.w};
#pragma unroll
    for (int r = 0; r < 4; ++r) {
        int row = n0 + q * 4 + r;
        if (row < N) {
            f16x8 xr = *(const f16x8*)(xh + (size_t)row * H + m * 8);
            f16x8 o;
            float fv[8];
#pragma unroll
            for (int ct = 0; ct < 8; ++ct) {
                float c = acc[ct][r] + bb[ct];
                float val = (float)xr[ct] + EPS * fast_tanh(c);
                o[ct] = (half_t)val;
                fv[ct] = val;
            }
            *(f16x8*)(xhout + (size_t)row * H + m * 8) = o;
            int lo = __builtin_amdgcn_cvt_pk_fp8_f32(fv[0], fv[1], 0, false);
            lo = __builtin_amdgcn_cvt_pk_fp8_f32(fv[2], fv[3], lo, true);
            int hi = __builtin_amdgcn_cvt_pk_fp8_f32(fv[4], fv[5], 0, false);
            hi = __builtin_amdgcn_cvt_pk_fp8_f32(fv[6], fv[7], hi, true);
            *(int2*)(xqout + (size_t)row * H + m * 8) = make_int2(lo, hi);
        }
    }
}

// ---------------- fused triple pooling + 2-layer MLP (one block per graph)
__global__ __launch_bounds__(1024) void pool_mlp(const half_t* __restrict__ x,
        const int* __restrict__ batch,
        const float* __restrict__ l1_w, const float* __restrict__ l1_b,
        const float* __restrict__ l2_w, const float* __restrict__ l2_b,
        float* __restrict__ out, int N) {
    __shared__ float ssum[8][128];
    __shared__ float smax[8][128];
    __shared__ __align__(16) float sp[384];
    __shared__ __align__(16) float sh[192];
    int g = blockIdx.x, t = threadIdx.x;
    int feat = t & 127, slot = t >> 7;   // 8 slots
    int lo = 0, hi = N;
    while (lo < hi) { int mid = (lo + hi) >> 1; if (batch[mid] < g) lo = mid + 1; else hi = mid; }
    int start = lo;
    hi = N;
    while (lo < hi) { int mid = (lo + hi) >> 1; if (batch[mid] < g + 1) lo = mid + 1; else hi = mid; }
    int end = lo;
    float sum = 0.f, mx = -INFINITY;
    for (int n = start + slot; n < end; n += 8) {
        float v = (float)x[(size_t)n * H + feat];
        sum += v;
        mx = fmaxf(mx, v);
    }
    ssum[slot][feat] = sum;
    smax[slot][feat] = mx;
    __syncthreads();
    if (t < 128) {
        float s = 0.f, m = -INFINITY;
#pragma unroll
        for (int k = 0; k < 8; ++k) { s += ssum[k][t]; m = fmaxf(m, smax[k][t]); }
        int cnt = end - start;
        sp[t] = s;
        sp[128 + t] = (cnt > 0) ? m : 0.f;
        sp[256 + t] = s / (float)(cnt > 0 ? cnt : 1);
    }
    __syncthreads();
    if (t < 192) {
        float acc = l1_b[t];
        const float* wr = l1_w + (size_t)t * 384;
        for (int k = 0; k < 384; k += 4) {
            float4 w = *(const float4*)(wr + k);
            float4 p = *(const float4*)(sp + k);
            acc += w.x * p.x + w.y * p.y + w.z * p.z + w.w * p.w;
        }
        sh[t] = acc > 0.f ? acc : NEG * acc;
    }
    __syncthreads();
    if (t < 64) {
        float acc = l2_b[t];
        const float* wr = l2_w + (size_t)t * 192;
        for (int k = 0; k < 192; k += 4) {
            float4 w = *(const float4*)(wr + k);
            float4 p = *(const float4*)(sh + k);
            acc += w.x * p.x + w.y * p.y + w.z * p.z + w.w * p.w;
        }
        out[g * 64 + t] = acc > 0.f ? acc : NEG * acc;
    }
}

extern "C" void kernel_launch(void* const* d_in, const int* in_sizes, int n_in,
                              void* d_out, int out_size, void* d_ws, size_t ws_size,
                              hipStream_t stream) {
    const float* x0    = (const float*)d_in[0];
    const int*   edge  = (const int*)d_in[1];
    const int*   batch = (const int*)d_in[2];
    const float* W     = (const float*)d_in[3];
    const float* bias  = (const float*)d_in[4];
    const float* lin_w = (const float*)d_in[5];
    const float* l1_w  = (const float*)d_in[6];
    const float* l1_b  = (const float*)d_in[7];
    const float* l2_w  = (const float*)d_in[8];
    const float* l2_b  = (const float*)d_in[9];
    float* out = (float*)d_out;

    int N = in_sizes[0] / H;
    int E = in_sizes[1] / 2;
    const int* src = edge;
    const int* dst = edge + E;

    size_t nh = (size_t)N * H;
    half_t* xhA    = (half_t*)d_ws;
    half_t* xhB    = xhA + nh;
    half_t* xaggh  = xhB + nh;
    half_t* WtTf   = xaggh + nh;              // 32768 halfs
    unsigned short* csr = (unsigned short*)(WtTf + 32768);   // N*ROWU16 u16
    unsigned char* xq   = (unsigned char*)(csr + (size_t)N * ROWU16);  // N*H fp8

    int n4 = (int)(nh / 4);
    prep_cast_zero<<<1024, 256, 0, stream>>>(W, lin_w, WtTf, x0, xhA, xq, csr, n4, N);

    fill_direct<<<(E + 255) / 256, 256, 0, stream>>>(src, dst, csr, E);

    const half_t* xcur_h = xhA;
    int nblocks = (N + CROWS - 1) / CROWS;
    for (int it = 0; it < 5; ++it) {
        gather_agg<<<2048, 256, 0, stream>>>(xq, csr, xaggh, N);
        half_t* xnext_h = (it & 1) ? xhA : xhB;
        conv_mfma<<<nblocks, 256, 0, stream>>>(xcur_h, xaggh, WtTf, bias, xnext_h, xq, N);
        xcur_h = xnext_h;
    }

    pool_mlp<<<NGRAPH, 1024, 0, stream>>>(xcur_h, batch, l1_w, l1_b, l2_w, l2_b, out, N);
}